// Round 15
// baseline (454.599 us; speedup 1.0000x reference)
//
#include <hip/hip_runtime.h>

#define N_NODES 10000
#define N_EDGES 160000

typedef float f32x4 __attribute__((ext_vector_type(4)));
typedef short s8v __attribute__((ext_vector_type(8)));
typedef short s4v __attribute__((ext_vector_type(4)));
typedef unsigned short u4s __attribute__((ext_vector_type(4)));

__device__ __forceinline__ unsigned short f2b(float f) {
    unsigned u = __builtin_bit_cast(unsigned, f);
    u += 0x7FFFu + ((u >> 16) & 1u);
    return (unsigned short)(u >> 16);
}
__device__ __forceinline__ float b2f(unsigned short s) {
    unsigned u = ((unsigned)s) << 16;
    return __builtin_bit_cast(float, u);
}

// ---------------- prep: weights -> bf16 layouts; nfv transpose; nfs convert ----------------
__global__ void k_prep(const float* s0, const float* s1, const float* s2, const float* s3,
                       const float* s4, const float* s5, const float* s6,
                       const float* s7, const float* s8, const float* nfv, const float* nfs,
                       unsigned short* d0, unsigned short* d1, unsigned short* d2, unsigned short* d3,
                       unsigned short* d4, unsigned short* d5, unsigned short* d6,
                       unsigned short* d7, unsigned short* d8,
                       unsigned short* nfvT, unsigned short* nfsB) {
    int idx = blockIdx.x * 256 + threadIdx.x;
    if (blockIdx.y < 2) {
        const float* src = blockIdx.y ? s1 : s0;
        unsigned short* dst = blockIdx.y ? d1 : d0;
        int k = idx >> 7, o = idx & 127;
        int ci = k / 10, a = k - ci * 10;
        dst[a * 16384 + o * 128 + ci] = f2b(src[idx]);
        return;
    }
    if (blockIdx.y == 9) {
        // nfv [n][c][i] f32 -> nfvT [i][n][c] bf16
        for (int ch = idx; ch < 960000; ch += 163840) {
            f32x4 v = *reinterpret_cast<const f32x4*>(nfv + (long)ch * 4);
            int f0 = ch * 4;
            int n = f0 / 384, rem = f0 - n * 384;
#pragma unroll
            for (int j = 0; j < 4; j++) {
                int f = rem + j;
                int cc = f / 3, ii = f - cc * 3;
                nfvT[ii * 1280000 + n * 128 + cc] = f2b(v[j]);
            }
        }
        return;
    }
    if (blockIdx.y == 10) {
        for (int ch = idx; ch < 320000; ch += 163840) {
            f32x4 v = *reinterpret_cast<const f32x4*>(nfs + (long)ch * 4);
#pragma unroll
            for (int j = 0; j < 4; j++) nfsB[ch * 4 + j] = f2b(v[j]);
        }
        return;
    }
    const float* src; unsigned short* dst; int K, Nc;
    switch (blockIdx.y) {
        case 2: src = s2; dst = d2; K = 128;  Nc = 128; break;
        case 3: src = s3; dst = d3; K = 128;  Nc = 128; break;
        case 4: src = s4; dst = d4; K = 256;  Nc = 128; break;
        case 5: src = s5; dst = d5; K = 384;  Nc = 128; break;
        case 6: src = s6; dst = d6; K = 64;   Nc = 640; break;
        case 7: src = s7; dst = d7; K = 64;   Nc = 64;  break;
        default: src = s8; dst = d8; K = 64;  Nc = 64;  break;
    }
    if (idx < K * Nc) {
        int k = idx / Nc, c = idx - k * Nc;
        dst[c * K + k] = f2b(src[idx]);
    }
}

// ---------------- sc + xpack fused, 32-row tiles, B read direct from L2 ----------------
// wave wv: rows (wv&1)*16..+16, cols (wv>>1)*64..+64
__global__ __launch_bounds__(256, 4) void k_sc(const unsigned short* __restrict__ nfsB,
                                               const unsigned short* __restrict__ nfvT,
                                               const float* __restrict__ attr,
                                               const unsigned short* __restrict__ Ws2,
                                               const unsigned short* __restrict__ Wv2,
                                               const unsigned short* __restrict__ wlin_sT,
                                               const unsigned short* __restrict__ wlin_vT,
                                               float* __restrict__ out, float scale,
                                               unsigned short* __restrict__ xpack, float scale2) {
    __shared__ unsigned short As[32][136];
    __shared__ float attr_l[32][10];
    const int t = threadIdx.x;
    const int z = blockIdx.y;
    const int row0 = blockIdx.x * 32;
    const int wv = t >> 6, lane = t & 63, lr = lane & 15, lkg = lane >> 4;
    const int wr = (wv & 1) * 16;       // wave row offset
    const int wc = (wv >> 1) * 64;      // wave col offset

    {
        int r = t >> 3, k0 = (t & 7) * 16;
        int row = row0 + r;
        if (row < N_NODES) {
            const unsigned short* asrc = (z == 0) ? (nfsB + (long)row * 128)
                                                  : (nfvT + (long)(z - 1) * 1280000 + (long)row * 128);
            *reinterpret_cast<s8v*>(&As[r][k0])     = *reinterpret_cast<const s8v*>(asrc + k0);
            *reinterpret_cast<s8v*>(&As[r][k0 + 8]) = *reinterpret_cast<const s8v*>(asrc + k0 + 8);
        } else {
#pragma unroll
            for (int j = 0; j < 16; j++) As[r][k0 + j] = 0;
        }
    }
    for (int idx = t; idx < 320; idx += 256) {
        int r = idx / 10, a = idx - r * 10;
        int row = row0 + r;
        attr_l[r][a] = (row < N_NODES) ? attr[row * 10 + a] : 0.f;
    }
    __syncthreads();

    s8v af[4];
#pragma unroll
    for (int kk = 0; kk < 4; kk++)
        af[kk] = *reinterpret_cast<const s8v*>(&As[wr + lr][kk * 32 + lkg * 8]);

    f32x4 accS[4];
#pragma unroll
    for (int i = 0; i < 4; i++) accS[i] = (f32x4){0.f, 0.f, 0.f, 0.f};

    const unsigned short* Wbase = (z == 0) ? Ws2 : Wv2;
    for (int a = 0; a < 10; a++) {
        const unsigned short* Wa = Wbase + a * 16384;
        f32x4 acc[4];
#pragma unroll
        for (int i = 0; i < 4; i++) acc[i] = (f32x4){0.f, 0.f, 0.f, 0.f};
#pragma unroll
        for (int kk = 0; kk < 4; kk++) {
#pragma unroll
            for (int ct = 0; ct < 4; ct++) {
                s8v bf = *reinterpret_cast<const s8v*>(Wa + (wc + ct * 16 + lr) * 128 + kk * 32 + lkg * 8);
                acc[ct] = __builtin_amdgcn_mfma_f32_16x16x32_bf16(af[kk], bf, acc[ct], 0, 0, 0);
            }
        }
#pragma unroll
        for (int r = 0; r < 4; r++) {
            float aw = attr_l[wr + lkg * 4 + r][a];
#pragma unroll
            for (int ct = 0; ct < 4; ct++)
                accS[ct][r] += aw * acc[ct][r];
        }
    }
#pragma unroll
    for (int ct = 0; ct < 4; ct++) {
#pragma unroll
        for (int r = 0; r < 4; r++) {
            int row = row0 + wr + lkg * 4 + r;
            if (row < N_NODES) {
                int col = wc + ct * 16 + lr;
                if (z == 0) out[(long)row * 512 + col] = accS[ct][r] * scale;
                else        out[(long)row * 512 + 128 + col * 3 + (z - 1)] = accS[ct][r] * scale;
            }
        }
    }
    // ---- fused xpack: x = A @ wlin * scale2 (reuses af fragments; wlin direct from L2) ----
    {
        const unsigned short* wl = (z == 0) ? wlin_sT : wlin_vT;
        f32x4 acc[4];
#pragma unroll
        for (int i = 0; i < 4; i++) acc[i] = (f32x4){0.f, 0.f, 0.f, 0.f};
#pragma unroll
        for (int kk = 0; kk < 4; kk++) {
#pragma unroll
            for (int ct = 0; ct < 4; ct++) {
                s8v bf = *reinterpret_cast<const s8v*>(wl + (wc + ct * 16 + lr) * 128 + kk * 32 + lkg * 8);
                acc[ct] = __builtin_amdgcn_mfma_f32_16x16x32_bf16(af[kk], bf, acc[ct], 0, 0, 0);
            }
        }
#pragma unroll
        for (int ct = 0; ct < 4; ct++) {
#pragma unroll
            for (int r = 0; r < 4; r++) {
                int row = row0 + wr + lkg * 4 + r;
                if (row < N_NODES) {
                    int col = wc + ct * 16 + lr;
                    xpack[(long)row * 512 + col * 4 + z] = f2b(acc[ct][r] * scale2);
                }
            }
        }
    }
}

// ---------------- generic MFMA GEMM (out GEMM) ----------------
struct GemmZ {
    const float* Ap;
    int ars, aks;
    const unsigned short* Bt;
    float* Cp;
    int crs, ccs;
    int K;
    float scale;
    int M;
    int obf16;
    int abf16;
};

__global__ __launch_bounds__(256) void k_gemm(GemmZ g0, GemmZ g1, GemmZ g2, GemmZ g3) {
    GemmZ g;
    switch (blockIdx.z) { case 0: g = g0; break; case 1: g = g1; break; case 2: g = g2; break; default: g = g3; }
    __shared__ unsigned short As[64][40];
    const int t = threadIdx.x;
    const int wv = t >> 6, lane = t & 63;
    const int lr = lane & 15, lkg = lane >> 4;
    const int row0 = blockIdx.x * 64;
    const int br = t >> 2;
    const int bk0 = (t & 3) * 8;
    const int arow = row0 + br;

    f32x4 acc[8];
#pragma unroll
    for (int i = 0; i < 8; i++) acc[i] = (f32x4){0.f, 0.f, 0.f, 0.f};

    for (int k0 = 0; k0 < g.K; k0 += 32) {
        s8v av;
        if (arow < g.M) {
            if (g.abf16) {
                const unsigned short* ap = (const unsigned short*)g.Ap + (long)arow * g.ars + k0 + bk0;
                av = *reinterpret_cast<const s8v*>(ap);
            } else if (g.aks == 1) {
                const float* ap = g.Ap + (long)arow * g.ars + k0 + bk0;
                f32x4 v0 = *reinterpret_cast<const f32x4*>(ap);
                f32x4 v1 = *reinterpret_cast<const f32x4*>(ap + 4);
                av[0] = (short)f2b(v0[0]); av[1] = (short)f2b(v0[1]);
                av[2] = (short)f2b(v0[2]); av[3] = (short)f2b(v0[3]);
                av[4] = (short)f2b(v1[0]); av[5] = (short)f2b(v1[1]);
                av[6] = (short)f2b(v1[2]); av[7] = (short)f2b(v1[3]);
            } else {
#pragma unroll
                for (int j = 0; j < 8; j++)
                    av[j] = (short)f2b(g.Ap[(long)arow * g.ars + (long)(k0 + bk0 + j) * g.aks]);
            }
        } else {
#pragma unroll
            for (int j = 0; j < 8; j++) av[j] = 0;
        }
        __syncthreads();
        *reinterpret_cast<s8v*>(&As[br][bk0]) = av;
        __syncthreads();
        s8v af = *reinterpret_cast<const s8v*>(&As[wv * 16 + lr][lkg * 8]);
#pragma unroll
        for (int ct = 0; ct < 8; ct++) {
            const unsigned short* bp = g.Bt + (long)(ct * 16 + lr) * g.K + k0 + lkg * 8;
            s8v bf = *reinterpret_cast<const s8v*>(bp);
            acc[ct] = __builtin_amdgcn_mfma_f32_16x16x32_bf16(af, bf, acc[ct], 0, 0, 0);
        }
    }
#pragma unroll
    for (int ct = 0; ct < 8; ct++) {
#pragma unroll
        for (int r = 0; r < 4; r++) {
            int row = row0 + wv * 16 + lkg * 4 + r;
            if (row < g.M) {
                int col = ct * 16 + lr;
                if (g.obf16)
                    ((unsigned short*)g.Cp)[(long)row * g.crs + col * g.ccs] = f2b(acc[ct][r] * g.scale);
                else
                    g.Cp[(long)row * g.crs + col * g.ccs] = acc[ct][r] * g.scale;
            }
        }
    }
}

// ---------------- MLP: layer0 VALU, layers 1-2 MFMA ----------------
__global__ __launch_bounds__(256) void k_mlp012(const float* __restrict__ ef, const float* __restrict__ w0,
                                                const unsigned short* __restrict__ w1T,
                                                const unsigned short* __restrict__ w2T,
                                                unsigned short* __restrict__ h2out) {
    __shared__ float efs[64][8];
    __shared__ unsigned short hA[64][72];
    __shared__ unsigned short hB[64][72];
    const int t = threadIdx.x;
    const long e0 = (long)blockIdx.x * 64;
#pragma unroll
    for (int j = 0; j < 2; j++) { int idx = t + j * 256; ((float*)efs)[idx] = ef[e0 * 8 + idx]; }
    const int o = t & 63, ebase = t >> 6;
    float w0r[8];
#pragma unroll
    for (int k = 0; k < 8; k++) w0r[k] = w0[k * 64 + o];
    __syncthreads();
#pragma unroll
    for (int j = 0; j < 16; j++) {
        int e = ebase * 16 + j;
        float acc = 0.f;
#pragma unroll
        for (int k = 0; k < 8; k++) acc += efs[e][k] * w0r[k];
        acc *= 0.35355339059f;
        hA[e][o] = f2b(acc / (1.f + __expf(-acc)));
    }
    __syncthreads();
    const int wv = t >> 6, lane = t & 63, lr = lane & 15, lkg = lane >> 4;
    {
        f32x4 acc1[4];
#pragma unroll
        for (int ct = 0; ct < 4; ct++) acc1[ct] = (f32x4){0.f, 0.f, 0.f, 0.f};
#pragma unroll
        for (int kk = 0; kk < 2; kk++) {
            s8v a = *reinterpret_cast<const s8v*>(&hA[wv * 16 + lr][kk * 32 + lkg * 8]);
#pragma unroll
            for (int ct = 0; ct < 4; ct++) {
                s8v b = *reinterpret_cast<const s8v*>(w1T + (ct * 16 + lr) * 64 + kk * 32 + lkg * 8);
                acc1[ct] = __builtin_amdgcn_mfma_f32_16x16x32_bf16(a, b, acc1[ct], 0, 0, 0);
            }
        }
#pragma unroll
        for (int ct = 0; ct < 4; ct++)
#pragma unroll
            for (int r = 0; r < 4; r++) {
                float v = acc1[ct][r] * 0.125f;
                hB[wv * 16 + lkg * 4 + r][ct * 16 + lr] = f2b(v / (1.f + __expf(-v)));
            }
    }
    __syncthreads();
    {
        f32x4 acc2[4];
#pragma unroll
        for (int ct = 0; ct < 4; ct++) acc2[ct] = (f32x4){0.f, 0.f, 0.f, 0.f};
#pragma unroll
        for (int kk = 0; kk < 2; kk++) {
            s8v a = *reinterpret_cast<const s8v*>(&hB[wv * 16 + lr][kk * 32 + lkg * 8]);
#pragma unroll
            for (int ct = 0; ct < 4; ct++) {
                s8v b = *reinterpret_cast<const s8v*>(w2T + (ct * 16 + lr) * 64 + kk * 32 + lkg * 8);
                acc2[ct] = __builtin_amdgcn_mfma_f32_16x16x32_bf16(a, b, acc2[ct], 0, 0, 0);
            }
        }
#pragma unroll
        for (int ct = 0; ct < 4; ct++)
#pragma unroll
            for (int r = 0; r < 4; r++) {
                float v = acc2[ct][r] * 0.125f;
                int row = wv * 16 + lkg * 4 + r;
                h2out[(e0 + row) * 64 + ct * 16 + lr] = f2b(v / (1.f + __expf(-v)));
            }
    }
}

// ---------------- CSR build ----------------
__global__ void k_hist(const int* __restrict__ rcv, int* __restrict__ cnt) {
    int e = blockIdx.x * 256 + threadIdx.x;
    if (e < N_EDGES) atomicAdd(&cnt[rcv[e]], 1);
}

__global__ __launch_bounds__(256) void k_scan(const int* __restrict__ cnt, int* __restrict__ base, int* __restrict__ cur) {
    __shared__ int s[256];
    const int t = threadIdx.x;
    const int c0 = t * 40;
    int sum = 0;
    for (int i = 0; i < 40; i++) sum += cnt[c0 + i];
    s[t] = sum;
    __syncthreads();
    for (int off = 1; off < 256; off <<= 1) {
        int v = (t >= off) ? s[t - off] : 0;
        __syncthreads();
        s[t] += v;
        __syncthreads();
    }
    int run = t ? s[t - 1] : 0;
    for (int i = 0; i < 40; i++) {
        int idx = c0 + i;
        if (idx <= N_NODES) { base[idx] = run; cur[idx] = run; }
        run += cnt[idx];
    }
}

__global__ void k_scatter(const int* __restrict__ rcv, int* __restrict__ cur, int* __restrict__ order) {
    int e = blockIdx.x * 256 + threadIdx.x;
    if (e < N_EDGES) {
        int p = atomicAdd(&cur[rcv[e]], 1);
        order[p] = e;
    }
}

// ---------------- fused per-edge: early gathers, b-reuse MFMA, transposed tpw, store-runs ----------------
__global__ __launch_bounds__(256, 3) void k_edge2(const unsigned short* __restrict__ h2,
                                                  const unsigned short* __restrict__ w3T,
                                                  const float* __restrict__ eattr,
                                                  const int* __restrict__ snd, const int* __restrict__ rcv,
                                                  const int* __restrict__ order,
                                                  const int* __restrict__ base,
                                                  const unsigned short* __restrict__ xpack,
                                                  float* __restrict__ msg_s, float* __restrict__ msg_v) {
    __shared__ char smem_u[5760];                 // union: h2s [32][72] u16 | mrg [128][11] f32
    __shared__ unsigned short tpwT[640 * 36];     // [col][edge], stride 36 u16 (72B, 8B-aligned)
    __shared__ float es_l[32];
    __shared__ float ev_l[32][3];
    __shared__ int sn_l[32], rc_l[32];
    __shared__ int bflags[3];
    unsigned short (*h2s)[72] = (unsigned short(*)[72])smem_u;
    float (*mrg)[11] = (float(*)[11])smem_u;
    const int t = threadIdx.x;
    const int j0 = blockIdx.x * 32;
    {
        int r = t >> 3, kk = (t & 7) * 8;
        int e = order[j0 + r];
        s8v v = *reinterpret_cast<const s8v*>(h2 + (long)e * 64 + kk);
        *reinterpret_cast<s8v*>(&h2s[r][kk]) = v;
    }
    if (t < 32) {
        int e = order[j0 + t];
        es_l[t] = eattr[e * 4 + 0];
        ev_l[t][0] = eattr[e * 4 + 1];
        ev_l[t][1] = eattr[e * 4 + 2];
        ev_l[t][2] = eattr[e * 4 + 3];
        sn_l[t] = snd[e];
        int rc = rcv[e];
        rc_l[t] = rc;
        if (t == 0)  bflags[0] = base[rc];
        if (t == 16) bflags[1] = base[rc];
        if (t == 31) bflags[2] = base[rc + 1];
    }
    __syncthreads();
    const int wv = t >> 6, lane = t & 63, lr = lane & 15, lkg = lane >> 4;
    const int c = t & 127, seg = t >> 7;

    // T14 async-split: issue the 16 random xpack gathers NOW; latency hides under MFMA phase
    u4s xpr[16];
#pragma unroll
    for (int i = 0; i < 16; i++)
        xpr[i] = *reinterpret_cast<const u4s*>(xpack + (long)sn_l[seg * 16 + i] * 512 + c * 4);

    s8v a00 = *reinterpret_cast<const s8v*>(&h2s[lr][lkg * 8]);
    s8v a01 = *reinterpret_cast<const s8v*>(&h2s[lr][32 + lkg * 8]);
    s8v a10 = *reinterpret_cast<const s8v*>(&h2s[16 + lr][lkg * 8]);
    s8v a11 = *reinterpret_cast<const s8v*>(&h2s[16 + lr][32 + lkg * 8]);
#pragma unroll
    for (int q = 0; q < 10; q++) {
        int co = (wv + 4 * q) * 16 + lr;
        const unsigned short* bp = w3T + (long)co * 64 + lkg * 8;
        s8v b0 = *reinterpret_cast<const s8v*>(bp);
        s8v b1 = *reinterpret_cast<const s8v*>(bp + 32);
        f32x4 ac0 = (f32x4){0.f, 0.f, 0.f, 0.f};
        f32x4 ac1 = (f32x4){0.f, 0.f, 0.f, 0.f};
        ac0 = __builtin_amdgcn_mfma_f32_16x16x32_bf16(a00, b0, ac0, 0, 0, 0);
        ac0 = __builtin_amdgcn_mfma_f32_16x16x32_bf16(a01, b1, ac0, 0, 0, 0);
        ac1 = __builtin_amdgcn_mfma_f32_16x16x32_bf16(a10, b0, ac1, 0, 0, 0);
        ac1 = __builtin_amdgcn_mfma_f32_16x16x32_bf16(a11, b1, ac1, 0, 0, 0);
        u4s p0, p1;
#pragma unroll
        for (int r = 0; r < 4; r++) {
            p0[r] = f2b(ac0[r] * 0.125f);
            p1[r] = f2b(ac1[r] * 0.125f);
        }
        *reinterpret_cast<u4s*>(&tpwT[co * 36 + lkg * 4]) = p0;
        *reinterpret_cast<u4s*>(&tpwT[co * 36 + 16 + lkg * 4]) = p1;
    }
    __syncthreads();

    s4v wsv[5][4];
#pragma unroll
    for (int q = 0; q < 5; q++)
#pragma unroll
        for (int j = 0; j < 4; j++)
            wsv[q][j] = *reinterpret_cast<const s4v*>(&tpwT[(q * 128 + c) * 36 + seg * 16 + j * 4]);

    float A[11], F[11];
#pragma unroll
    for (int q = 0; q < 11; q++) { A[q] = 0.f; F[q] = 0.f; }
    int cur_rc = rc_l[seg * 16];
    int Frc = -1;

#define STORE_RUN(RC, SRC) do { \
        float* ms = msg_s + (long)(RC) * 256 + c; \
        ms[0] = SRC[0]; ms[128] = SRC[1]; \
        float* mv = msg_v + (long)(RC) * 1152 + c; \
        mv[0] = SRC[2]; mv[128] = SRC[3]; mv[256] = SRC[4]; \
        mv[384] = SRC[5]; mv[512] = SRC[6]; mv[640] = SRC[7]; \
        mv[768] = SRC[8]; mv[896] = SRC[9]; mv[1024] = SRC[10]; \
    } while (0)
#define ATOM_RUN(RC, SRC) do { \
        float* ms = msg_s + (long)(RC) * 256 + c; \
        unsafeAtomicAdd(ms, SRC[0]); unsafeAtomicAdd(ms + 128, SRC[1]); \
        float* mv = msg_v + (long)(RC) * 1152 + c; \
        unsafeAtomicAdd(mv + 0, SRC[2]); unsafeAtomicAdd(mv + 128, SRC[3]); \
        unsafeAtomicAdd(mv + 256, SRC[4]); unsafeAtomicAdd(mv + 384, SRC[5]); \
        unsafeAtomicAdd(mv + 512, SRC[6]); unsafeAtomicAdd(mv + 640, SRC[7]); \
        unsafeAtomicAdd(mv + 768, SRC[8]); unsafeAtomicAdd(mv + 896, SRC[9]); \
        unsafeAtomicAdd(mv + 1024, SRC[10]); \
    } while (0)

#pragma unroll
    for (int i = 0; i < 16; i++) {
        int idx = seg * 16 + i;
        int rc = rc_l[idx];
        if (rc != cur_rc) {
            if (Frc < 0) {
#pragma unroll
                for (int q = 0; q < 11; q++) { F[q] = A[q]; A[q] = 0.f; }
                Frc = cur_rc;
            } else {
                STORE_RUN(cur_rc, A);
#pragma unroll
                for (int q = 0; q < 11; q++) A[q] = 0.f;
            }
            cur_rc = rc;
        }
        float es = es_l[idx], ev0 = ev_l[idx][0], ev1 = ev_l[idx][1], ev2 = ev_l[idx][2];
        float w1 = b2f((unsigned short)wsv[0][i >> 2][i & 3]);
        float w2 = b2f((unsigned short)wsv[1][i >> 2][i & 3]);
        float w3 = b2f((unsigned short)wsv[2][i >> 2][i & 3]);
        float w4 = b2f((unsigned short)wsv[3][i >> 2][i & 3]);
        float w5 = b2f((unsigned short)wsv[4][i >> 2][i & 3]);
        float xsv = b2f(xpr[i][0]);
        float x0 = b2f(xpr[i][1]), x1 = b2f(xpr[i][2]), x2 = b2f(xpr[i][3]);
        A[0] += w1 * xsv * es;
        float dve = x0 * ev0 + x1 * ev1 + x2 * ev2;
        A[1] += w4 * dve * 0.57735026919f;
        float a2 = w2 * xsv;
        A[2] += a2 * ev0;
        A[3] += w3 * x0 * es;
        A[4] += w5 * (x1 * ev2 - x2 * ev1) * 0.70710678119f;
        A[5] += a2 * ev1;
        A[6] += w3 * x1 * es;
        A[7] += w5 * (x2 * ev0 - x0 * ev2) * 0.70710678119f;
        A[8] += a2 * ev2;
        A[9] += w3 * x2 * es;
        A[10] += w5 * (x0 * ev1 - x1 * ev0) * 0.70710678119f;
    }
    const bool merge = (rc_l[15] == rc_l[16]);
    if (seg == 0) {
        if (merge) {
#pragma unroll
            for (int q = 0; q < 11; q++) mrg[c][q] = A[q];
            if (Frc >= 0) {
                if (bflags[0] == j0) STORE_RUN(Frc, F); else ATOM_RUN(Frc, F);
            }
        } else {
            if (Frc < 0) {
                if (bflags[0] == j0) STORE_RUN(cur_rc, A); else ATOM_RUN(cur_rc, A);
            } else {
                if (bflags[0] == j0) STORE_RUN(Frc, F); else ATOM_RUN(Frc, F);
                STORE_RUN(cur_rc, A);
            }
        }
    } else {
        if (!merge) {
            if (Frc < 0) {
                if (bflags[2] == j0 + 32) STORE_RUN(cur_rc, A); else ATOM_RUN(cur_rc, A);
            } else {
                STORE_RUN(Frc, F);
                if (bflags[2] == j0 + 32) STORE_RUN(cur_rc, A); else ATOM_RUN(cur_rc, A);
            }
        }
    }
    __syncthreads();
    if (seg == 1 && merge) {
        if (Frc < 0) {
#pragma unroll
            for (int q = 0; q < 11; q++) A[q] += mrg[c][q];
            bool st = (bflags[1] >= j0) && (bflags[2] == j0 + 32);
            if (st) STORE_RUN(cur_rc, A); else ATOM_RUN(cur_rc, A);
        } else {
#pragma unroll
            for (int q = 0; q < 11; q++) F[q] += mrg[c][q];
            if (bflags[1] >= j0) STORE_RUN(Frc, F); else ATOM_RUN(Frc, F);
            if (bflags[2] == j0 + 32) STORE_RUN(cur_rc, A); else ATOM_RUN(cur_rc, A);
        }
    }
#undef STORE_RUN
#undef ATOM_RUN
}

extern "C" void kernel_launch(void* const* d_in, const int* in_sizes, int n_in,
                              void* d_out, int out_size, void* d_ws, size_t ws_size,
                              hipStream_t stream) {
    const float* node_attrs = (const float*)d_in[0];
    const float* nfs        = (const float*)d_in[1];
    const float* nfv        = (const float*)d_in[2];
    const float* edge_attrs = (const float*)d_in[3];
    const float* edge_feats = (const float*)d_in[4];
    const float* W_sc_s     = (const float*)d_in[5];
    const float* W_sc_v     = (const float*)d_in[6];
    const float* W_lin_s    = (const float*)d_in[7];
    const float* W_lin_v    = (const float*)d_in[8];
    const float* mlp_w0     = (const float*)d_in[9];
    const float* mlp_w1     = (const float*)d_in[10];
    const float* mlp_w2     = (const float*)d_in[11];
    const float* mlp_w3     = (const float*)d_in[12];
    const float* W_out_s    = (const float*)d_in[13];
    const float* W_out_v    = (const float*)d_in[14];
    const int* senders      = (const int*)d_in[15];
    const int* receivers    = (const int*)d_in[16];
    float* dout = (float*)d_out;

    char* W = (char*)d_ws;
    unsigned short* xpack_ws = (unsigned short*)(W + 0);        // 10,240,000
    float* msgs_ws = (float*)(W + 10240000);   // 10,240,000
    float* msgv_ws = (float*)(W + 20480000);   // 46,080,000 -> ends 66,560,000
    // nfvT/nfsB alias the msgv region (consumed before memset/edge2 write it)
    unsigned short* nfvT_ws = (unsigned short*)(W + 20480000);  // 7,680,000
    unsigned short* nfsB_ws = (unsigned short*)(W + 28160000);  // 2,560,000 -> ends 30,720,000
    unsigned short* h2_ws   = (unsigned short*)(W + 66560000);  // 20,480,000 -> ends 87,040,000
    unsigned short* wsc_s2  = (unsigned short*)(W + 87040000);
    unsigned short* wsc_v2  = (unsigned short*)(W + 87367680);
    unsigned short* wlin_sT = (unsigned short*)(W + 87695360);
    unsigned short* wlin_vT = (unsigned short*)(W + 87728128);
    unsigned short* wout_sT = (unsigned short*)(W + 87760896);
    unsigned short* wout_vT = (unsigned short*)(W + 87826432);
    unsigned short* w3T     = (unsigned short*)(W + 87924736);
    unsigned short* w1T     = (unsigned short*)(W + 88006656);
    unsigned short* w2T     = (unsigned short*)(W + 88014848);
    int* cnt_ws   = (int*)(W + 88023040);
    int* base_ws  = (int*)(W + 88064000);
    int* cur_ws   = (int*)(W + 88104960);
    int* order_ws = (int*)(W + 88145920);   // ends 88,785,920

    const float inv1280 = 0.02795084972f;
    const float inv128  = 0.08838834765f;
    const float scO_s   = 1.f / 256.f;
    const float scO_v   = 1.f / (19.5959179423f * 16.f);

    k_prep<<<dim3(640, 11, 1), 256, 0, stream>>>(W_sc_s, W_sc_v, W_lin_s, W_lin_v, W_out_s, W_out_v, mlp_w3,
                                                 mlp_w1, mlp_w2, nfv, nfs,
                                                 wsc_s2, wsc_v2, wlin_sT, wlin_vT, wout_sT, wout_vT, w3T,
                                                 w1T, w2T, nfvT_ws, nfsB_ws);
    k_mlp012<<<dim3(2500), 256, 0, stream>>>(edge_feats, mlp_w0, w1T, w2T, h2_ws);

    // sc -> d_out second half  +  fused xpack (bf16 [n][c][4]), 32-row tiles, direct-L2 B
    k_sc<<<dim3(313, 4), 256, 0, stream>>>(nfsB_ws, nfvT_ws, node_attrs, wsc_s2, wsc_v2,
                                           wlin_sT, wlin_vT, dout + 5120000, inv1280,
                                           xpack_ws, inv128);

    hipMemsetAsync(msgs_ws, 0, 56320000, stream);  // msg_s + msg_v (overwrites nfvT/nfsB alias)
    hipMemsetAsync(cnt_ws, 0, 40960, stream);
    k_hist<<<dim3(625), 256, 0, stream>>>(receivers, cnt_ws);
    k_scan<<<dim3(1), 256, 0, stream>>>(cnt_ws, base_ws, cur_ws);
    k_scatter<<<dim3(625), 256, 0, stream>>>(receivers, cur_ws, order_ws);
    k_edge2<<<dim3(5000), 256, 0, stream>>>(h2_ws, w3T, edge_attrs, senders, receivers, order_ws,
                                            base_ws, xpack_ws, msgs_ws, msgv_ws);

    // out = msg @ W_out -> d_out first half
    {
        GemmZ g0{msgs_ws,       256,  1, wout_sT, dout,           512, 1, 256, scO_s, N_NODES, 0, 0};
        GemmZ g1{msgv_ws + 0,   1152, 1, wout_vT, dout + 128 + 0, 512, 3, 384, scO_v, N_NODES, 0, 0};
        GemmZ g2{msgv_ws + 384, 1152, 1, wout_vT, dout + 128 + 1, 512, 3, 384, scO_v, N_NODES, 0, 0};
        GemmZ g3{msgv_ws + 768, 1152, 1, wout_vT, dout + 128 + 2, 512, 3, 384, scO_v, N_NODES, 0, 0};
        k_gemm<<<dim3(157, 1, 4), 256, 0, stream>>>(g0, g1, g2, g3);
    }
}

// Round 16
// 284.678 us; speedup vs baseline: 1.5969x; 1.5969x over previous
//
#include <hip/hip_runtime.h>

#define N_NODES 10000
#define N_EDGES 160000

typedef float f32x4 __attribute__((ext_vector_type(4)));
typedef short s8v __attribute__((ext_vector_type(8)));
typedef short s4v __attribute__((ext_vector_type(4)));
typedef unsigned short u4s __attribute__((ext_vector_type(4)));

__device__ __forceinline__ unsigned short f2b(float f) {
    unsigned u = __builtin_bit_cast(unsigned, f);
    u += 0x7FFFu + ((u >> 16) & 1u);
    return (unsigned short)(u >> 16);
}
__device__ __forceinline__ float b2f(unsigned short s) {
    unsigned u = ((unsigned)s) << 16;
    return __builtin_bit_cast(float, u);
}

// ---------------- prep: weights -> bf16 layouts; nfv transpose; nfs convert ----------------
__global__ void k_prep(const float* s0, const float* s1, const float* s2, const float* s3,
                       const float* s4, const float* s5, const float* s6,
                       const float* s7, const float* s8, const float* nfv, const float* nfs,
                       unsigned short* d0, unsigned short* d1, unsigned short* d2, unsigned short* d3,
                       unsigned short* d4, unsigned short* d5, unsigned short* d6,
                       unsigned short* d7, unsigned short* d8,
                       unsigned short* nfvT, unsigned short* nfsB) {
    int idx = blockIdx.x * 256 + threadIdx.x;
    if (blockIdx.y < 2) {
        const float* src = blockIdx.y ? s1 : s0;
        unsigned short* dst = blockIdx.y ? d1 : d0;
        int k = idx >> 7, o = idx & 127;
        int ci = k / 10, a = k - ci * 10;
        dst[a * 16384 + o * 128 + ci] = f2b(src[idx]);
        return;
    }
    if (blockIdx.y == 9) {
        // nfv [n][c][i] f32 -> nfvT [i][n][c] bf16
        for (int ch = idx; ch < 960000; ch += 163840) {
            f32x4 v = *reinterpret_cast<const f32x4*>(nfv + (long)ch * 4);
            int f0 = ch * 4;
            int n = f0 / 384, rem = f0 - n * 384;
#pragma unroll
            for (int j = 0; j < 4; j++) {
                int f = rem + j;
                int cc = f / 3, ii = f - cc * 3;
                nfvT[ii * 1280000 + n * 128 + cc] = f2b(v[j]);
            }
        }
        return;
    }
    if (blockIdx.y == 10) {
        for (int ch = idx; ch < 320000; ch += 163840) {
            f32x4 v = *reinterpret_cast<const f32x4*>(nfs + (long)ch * 4);
#pragma unroll
            for (int j = 0; j < 4; j++) nfsB[ch * 4 + j] = f2b(v[j]);
        }
        return;
    }
    const float* src; unsigned short* dst; int K, Nc;
    switch (blockIdx.y) {
        case 2: src = s2; dst = d2; K = 128;  Nc = 128; break;
        case 3: src = s3; dst = d3; K = 128;  Nc = 128; break;
        case 4: src = s4; dst = d4; K = 256;  Nc = 128; break;
        case 5: src = s5; dst = d5; K = 384;  Nc = 128; break;
        case 6: src = s6; dst = d6; K = 64;   Nc = 640; break;
        case 7: src = s7; dst = d7; K = 64;   Nc = 64;  break;
        default: src = s8; dst = d8; K = 64;  Nc = 64;  break;
    }
    if (idx < K * Nc) {
        int k = idx / Nc, c = idx - k * Nc;
        dst[c * K + k] = f2b(src[idx]);
    }
}

// ---------------- sc + xpack fused: 64x128 tile, 512 threads / 8 waves ----------------
// wave wv: rows (wv&3)*16..+16, cols (wv>>2)*64..+64
__global__ __launch_bounds__(512, 2) void k_sc(const unsigned short* __restrict__ nfsB,
                                               const unsigned short* __restrict__ nfvT,
                                               const float* __restrict__ attr,
                                               const unsigned short* __restrict__ Ws2,
                                               const unsigned short* __restrict__ Wv2,
                                               const unsigned short* __restrict__ wlin_sT,
                                               const unsigned short* __restrict__ wlin_vT,
                                               float* __restrict__ out, float scale,
                                               unsigned short* __restrict__ xpack, float scale2) {
    __shared__ unsigned short As[64][136];
    __shared__ unsigned short Bs[128][140];
    __shared__ float attr_l[64][10];
    const int t = threadIdx.x;
    const int z = blockIdx.y;
    const int row0 = blockIdx.x * 64;
    const int wv = t >> 6, lane = t & 63, lr = lane & 15, lkg = lane >> 4;
    const int wr = (wv & 3) * 16;       // wave row offset
    const int wc = (wv >> 2) * 64;      // wave col offset

    {
        int r = t >> 3, k0 = (t & 7) * 16;
        int row = row0 + r;
        if (row < N_NODES) {
            const unsigned short* asrc = (z == 0) ? (nfsB + (long)row * 128)
                                                  : (nfvT + (long)(z - 1) * 1280000 + (long)row * 128);
            *reinterpret_cast<s8v*>(&As[r][k0])     = *reinterpret_cast<const s8v*>(asrc + k0);
            *reinterpret_cast<s8v*>(&As[r][k0 + 8]) = *reinterpret_cast<const s8v*>(asrc + k0 + 8);
        } else {
#pragma unroll
            for (int j = 0; j < 16; j++) As[r][k0 + j] = 0;
        }
    }
    for (int idx = t; idx < 640; idx += 512) {
        int r = idx / 10, a = idx - r * 10;
        int row = row0 + r;
        attr_l[r][a] = (row < N_NODES) ? attr[row * 10 + a] : 0.f;
    }
    __syncthreads();

    s8v af[4];
#pragma unroll
    for (int kk = 0; kk < 4; kk++)
        af[kk] = *reinterpret_cast<const s8v*>(&As[wr + lr][kk * 32 + lkg * 8]);

    f32x4 accS[4];
#pragma unroll
    for (int i = 0; i < 4; i++) accS[i] = (f32x4){0.f, 0.f, 0.f, 0.f};

    const unsigned short* Wbase = (z == 0) ? Ws2 : Wv2;
    for (int a = 0; a < 10; a++) {
        {
            const unsigned short* src = Wbase + a * 16384;
            int r = t >> 2, c0 = (t & 3) * 32;
#pragma unroll
            for (int j = 0; j < 4; j++) {
                s8v v = *reinterpret_cast<const s8v*>(src + r * 128 + c0 + j * 8);
                *reinterpret_cast<s8v*>(&Bs[r][c0 + j * 8]) = v;
            }
        }
        __syncthreads();
        f32x4 acc[4];
#pragma unroll
        for (int i = 0; i < 4; i++) acc[i] = (f32x4){0.f, 0.f, 0.f, 0.f};
#pragma unroll
        for (int kk = 0; kk < 4; kk++) {
#pragma unroll
            for (int ct = 0; ct < 4; ct++) {
                s8v bf = *reinterpret_cast<const s8v*>(&Bs[wc + ct * 16 + lr][kk * 32 + lkg * 8]);
                acc[ct] = __builtin_amdgcn_mfma_f32_16x16x32_bf16(af[kk], bf, acc[ct], 0, 0, 0);
            }
        }
#pragma unroll
        for (int r = 0; r < 4; r++) {
            float aw = attr_l[wr + lkg * 4 + r][a];
#pragma unroll
            for (int ct = 0; ct < 4; ct++)
                accS[ct][r] += aw * acc[ct][r];
        }
        __syncthreads();
    }
#pragma unroll
    for (int ct = 0; ct < 4; ct++) {
#pragma unroll
        for (int r = 0; r < 4; r++) {
            int row = row0 + wr + lkg * 4 + r;
            if (row < N_NODES) {
                int col = wc + ct * 16 + lr;
                if (z == 0) out[(long)row * 512 + col] = accS[ct][r] * scale;
                else        out[(long)row * 512 + 128 + col * 3 + (z - 1)] = accS[ct][r] * scale;
            }
        }
    }
    // ---- fused xpack: x = A @ wlin * scale2 (reuses af fragments) ----
    {
        const unsigned short* wl = (z == 0) ? wlin_sT : wlin_vT;
        {
            int r = t >> 2, c0 = (t & 3) * 32;
#pragma unroll
            for (int j = 0; j < 4; j++) {
                s8v v = *reinterpret_cast<const s8v*>(wl + r * 128 + c0 + j * 8);
                *reinterpret_cast<s8v*>(&Bs[r][c0 + j * 8]) = v;
            }
        }
        __syncthreads();
        f32x4 acc[4];
#pragma unroll
        for (int i = 0; i < 4; i++) acc[i] = (f32x4){0.f, 0.f, 0.f, 0.f};
#pragma unroll
        for (int kk = 0; kk < 4; kk++) {
#pragma unroll
            for (int ct = 0; ct < 4; ct++) {
                s8v bf = *reinterpret_cast<const s8v*>(&Bs[wc + ct * 16 + lr][kk * 32 + lkg * 8]);
                acc[ct] = __builtin_amdgcn_mfma_f32_16x16x32_bf16(af[kk], bf, acc[ct], 0, 0, 0);
            }
        }
#pragma unroll
        for (int ct = 0; ct < 4; ct++) {
#pragma unroll
            for (int r = 0; r < 4; r++) {
                int row = row0 + wr + lkg * 4 + r;
                if (row < N_NODES) {
                    int col = wc + ct * 16 + lr;
                    xpack[(long)row * 512 + col * 4 + z] = f2b(acc[ct][r] * scale2);
                }
            }
        }
    }
}

// ---------------- generic MFMA GEMM (out GEMM) ----------------
struct GemmZ {
    const float* Ap;
    int ars, aks;
    const unsigned short* Bt;
    float* Cp;
    int crs, ccs;
    int K;
    float scale;
    int M;
    int obf16;
    int abf16;
};

__global__ __launch_bounds__(256) void k_gemm(GemmZ g0, GemmZ g1, GemmZ g2, GemmZ g3) {
    GemmZ g;
    switch (blockIdx.z) { case 0: g = g0; break; case 1: g = g1; break; case 2: g = g2; break; default: g = g3; }
    __shared__ unsigned short As[64][40];
    const int t = threadIdx.x;
    const int wv = t >> 6, lane = t & 63;
    const int lr = lane & 15, lkg = lane >> 4;
    const int row0 = blockIdx.x * 64;
    const int br = t >> 2;
    const int bk0 = (t & 3) * 8;
    const int arow = row0 + br;

    f32x4 acc[8];
#pragma unroll
    for (int i = 0; i < 8; i++) acc[i] = (f32x4){0.f, 0.f, 0.f, 0.f};

    for (int k0 = 0; k0 < g.K; k0 += 32) {
        s8v av;
        if (arow < g.M) {
            if (g.abf16) {
                const unsigned short* ap = (const unsigned short*)g.Ap + (long)arow * g.ars + k0 + bk0;
                av = *reinterpret_cast<const s8v*>(ap);
            } else if (g.aks == 1) {
                const float* ap = g.Ap + (long)arow * g.ars + k0 + bk0;
                f32x4 v0 = *reinterpret_cast<const f32x4*>(ap);
                f32x4 v1 = *reinterpret_cast<const f32x4*>(ap + 4);
                av[0] = (short)f2b(v0[0]); av[1] = (short)f2b(v0[1]);
                av[2] = (short)f2b(v0[2]); av[3] = (short)f2b(v0[3]);
                av[4] = (short)f2b(v1[0]); av[5] = (short)f2b(v1[1]);
                av[6] = (short)f2b(v1[2]); av[7] = (short)f2b(v1[3]);
            } else {
#pragma unroll
                for (int j = 0; j < 8; j++)
                    av[j] = (short)f2b(g.Ap[(long)arow * g.ars + (long)(k0 + bk0 + j) * g.aks]);
            }
        } else {
#pragma unroll
            for (int j = 0; j < 8; j++) av[j] = 0;
        }
        __syncthreads();
        *reinterpret_cast<s8v*>(&As[br][bk0]) = av;
        __syncthreads();
        s8v af = *reinterpret_cast<const s8v*>(&As[wv * 16 + lr][lkg * 8]);
#pragma unroll
        for (int ct = 0; ct < 8; ct++) {
            const unsigned short* bp = g.Bt + (long)(ct * 16 + lr) * g.K + k0 + lkg * 8;
            s8v bf = *reinterpret_cast<const s8v*>(bp);
            acc[ct] = __builtin_amdgcn_mfma_f32_16x16x32_bf16(af, bf, acc[ct], 0, 0, 0);
        }
    }
#pragma unroll
    for (int ct = 0; ct < 8; ct++) {
#pragma unroll
        for (int r = 0; r < 4; r++) {
            int row = row0 + wv * 16 + lkg * 4 + r;
            if (row < g.M) {
                int col = ct * 16 + lr;
                if (g.obf16)
                    ((unsigned short*)g.Cp)[(long)row * g.crs + col * g.ccs] = f2b(acc[ct][r] * g.scale);
                else
                    g.Cp[(long)row * g.crs + col * g.ccs] = acc[ct][r] * g.scale;
            }
        }
    }
}

// ---------------- MLP: layer0 VALU, layers 1-2 MFMA ----------------
__global__ __launch_bounds__(256) void k_mlp012(const float* __restrict__ ef, const float* __restrict__ w0,
                                                const unsigned short* __restrict__ w1T,
                                                const unsigned short* __restrict__ w2T,
                                                unsigned short* __restrict__ h2out) {
    __shared__ float efs[64][8];
    __shared__ unsigned short hA[64][72];
    __shared__ unsigned short hB[64][72];
    const int t = threadIdx.x;
    const long e0 = (long)blockIdx.x * 64;
#pragma unroll
    for (int j = 0; j < 2; j++) { int idx = t + j * 256; ((float*)efs)[idx] = ef[e0 * 8 + idx]; }
    const int o = t & 63, ebase = t >> 6;
    float w0r[8];
#pragma unroll
    for (int k = 0; k < 8; k++) w0r[k] = w0[k * 64 + o];
    __syncthreads();
#pragma unroll
    for (int j = 0; j < 16; j++) {
        int e = ebase * 16 + j;
        float acc = 0.f;
#pragma unroll
        for (int k = 0; k < 8; k++) acc += efs[e][k] * w0r[k];
        acc *= 0.35355339059f;
        hA[e][o] = f2b(acc / (1.f + __expf(-acc)));
    }
    __syncthreads();
    const int wv = t >> 6, lane = t & 63, lr = lane & 15, lkg = lane >> 4;
    {
        f32x4 acc1[4];
#pragma unroll
        for (int ct = 0; ct < 4; ct++) acc1[ct] = (f32x4){0.f, 0.f, 0.f, 0.f};
#pragma unroll
        for (int kk = 0; kk < 2; kk++) {
            s8v a = *reinterpret_cast<const s8v*>(&hA[wv * 16 + lr][kk * 32 + lkg * 8]);
#pragma unroll
            for (int ct = 0; ct < 4; ct++) {
                s8v b = *reinterpret_cast<const s8v*>(w1T + (ct * 16 + lr) * 64 + kk * 32 + lkg * 8);
                acc1[ct] = __builtin_amdgcn_mfma_f32_16x16x32_bf16(a, b, acc1[ct], 0, 0, 0);
            }
        }
#pragma unroll
        for (int ct = 0; ct < 4; ct++)
#pragma unroll
            for (int r = 0; r < 4; r++) {
                float v = acc1[ct][r] * 0.125f;
                hB[wv * 16 + lkg * 4 + r][ct * 16 + lr] = f2b(v / (1.f + __expf(-v)));
            }
    }
    __syncthreads();
    {
        f32x4 acc2[4];
#pragma unroll
        for (int ct = 0; ct < 4; ct++) acc2[ct] = (f32x4){0.f, 0.f, 0.f, 0.f};
#pragma unroll
        for (int kk = 0; kk < 2; kk++) {
            s8v a = *reinterpret_cast<const s8v*>(&hB[wv * 16 + lr][kk * 32 + lkg * 8]);
#pragma unroll
            for (int ct = 0; ct < 4; ct++) {
                s8v b = *reinterpret_cast<const s8v*>(w2T + (ct * 16 + lr) * 64 + kk * 32 + lkg * 8);
                acc2[ct] = __builtin_amdgcn_mfma_f32_16x16x32_bf16(a, b, acc2[ct], 0, 0, 0);
            }
        }
#pragma unroll
        for (int ct = 0; ct < 4; ct++)
#pragma unroll
            for (int r = 0; r < 4; r++) {
                float v = acc2[ct][r] * 0.125f;
                int row = wv * 16 + lkg * 4 + r;
                h2out[(e0 + row) * 64 + ct * 16 + lr] = f2b(v / (1.f + __expf(-v)));
            }
    }
}

// ---------------- CSR build ----------------
__global__ void k_hist(const int* __restrict__ rcv, int* __restrict__ cnt) {
    int e = blockIdx.x * 256 + threadIdx.x;
    if (e < N_EDGES) atomicAdd(&cnt[rcv[e]], 1);
}

__global__ __launch_bounds__(256) void k_scan(const int* __restrict__ cnt, int* __restrict__ base, int* __restrict__ cur) {
    __shared__ int s[256];
    const int t = threadIdx.x;
    const int c0 = t * 40;
    int sum = 0;
    for (int i = 0; i < 40; i++) sum += cnt[c0 + i];
    s[t] = sum;
    __syncthreads();
    for (int off = 1; off < 256; off <<= 1) {
        int v = (t >= off) ? s[t - off] : 0;
        __syncthreads();
        s[t] += v;
        __syncthreads();
    }
    int run = t ? s[t - 1] : 0;
    for (int i = 0; i < 40; i++) {
        int idx = c0 + i;
        if (idx <= N_NODES) { base[idx] = run; cur[idx] = run; }
        run += cnt[idx];
    }
}

__global__ void k_scatter(const int* __restrict__ rcv, int* __restrict__ cur, int* __restrict__ order) {
    int e = blockIdx.x * 256 + threadIdx.x;
    if (e < N_EDGES) {
        int p = atomicAdd(&cur[rcv[e]], 1);
        order[p] = e;
    }
}

// ---------------- fused per-edge: early gathers, b-reuse MFMA, transposed tpw, store-runs ----------------
__global__ __launch_bounds__(256, 3) void k_edge2(const unsigned short* __restrict__ h2,
                                                  const unsigned short* __restrict__ w3T,
                                                  const float* __restrict__ eattr,
                                                  const int* __restrict__ snd, const int* __restrict__ rcv,
                                                  const int* __restrict__ order,
                                                  const int* __restrict__ base,
                                                  const unsigned short* __restrict__ xpack,
                                                  float* __restrict__ msg_s, float* __restrict__ msg_v) {
    __shared__ char smem_u[5760];                 // union: h2s [32][72] u16 | mrg [128][11] f32
    __shared__ unsigned short tpwT[640 * 36];     // [col][edge], stride 36 u16 (72B, 8B-aligned)
    __shared__ float es_l[32];
    __shared__ float ev_l[32][3];
    __shared__ int sn_l[32], rc_l[32];
    __shared__ int bflags[3];
    unsigned short (*h2s)[72] = (unsigned short(*)[72])smem_u;
    float (*mrg)[11] = (float(*)[11])smem_u;
    const int t = threadIdx.x;
    const int j0 = blockIdx.x * 32;
    {
        int r = t >> 3, kk = (t & 7) * 8;
        int e = order[j0 + r];
        s8v v = *reinterpret_cast<const s8v*>(h2 + (long)e * 64 + kk);
        *reinterpret_cast<s8v*>(&h2s[r][kk]) = v;
    }
    if (t < 32) {
        int e = order[j0 + t];
        es_l[t] = eattr[e * 4 + 0];
        ev_l[t][0] = eattr[e * 4 + 1];
        ev_l[t][1] = eattr[e * 4 + 2];
        ev_l[t][2] = eattr[e * 4 + 3];
        sn_l[t] = snd[e];
        int rc = rcv[e];
        rc_l[t] = rc;
        if (t == 0)  bflags[0] = base[rc];
        if (t == 16) bflags[1] = base[rc];
        if (t == 31) bflags[2] = base[rc + 1];
    }
    __syncthreads();
    const int wv = t >> 6, lane = t & 63, lr = lane & 15, lkg = lane >> 4;
    const int c = t & 127, seg = t >> 7;

    // T14 async-split: issue the 16 random xpack gathers NOW; latency hides under MFMA phase
    u4s xpr[16];
#pragma unroll
    for (int i = 0; i < 16; i++)
        xpr[i] = *reinterpret_cast<const u4s*>(xpack + (long)sn_l[seg * 16 + i] * 512 + c * 4);

    s8v a00 = *reinterpret_cast<const s8v*>(&h2s[lr][lkg * 8]);
    s8v a01 = *reinterpret_cast<const s8v*>(&h2s[lr][32 + lkg * 8]);
    s8v a10 = *reinterpret_cast<const s8v*>(&h2s[16 + lr][lkg * 8]);
    s8v a11 = *reinterpret_cast<const s8v*>(&h2s[16 + lr][32 + lkg * 8]);
#pragma unroll
    for (int q = 0; q < 10; q++) {
        int co = (wv + 4 * q) * 16 + lr;
        const unsigned short* bp = w3T + (long)co * 64 + lkg * 8;
        s8v b0 = *reinterpret_cast<const s8v*>(bp);
        s8v b1 = *reinterpret_cast<const s8v*>(bp + 32);
        f32x4 ac0 = (f32x4){0.f, 0.f, 0.f, 0.f};
        f32x4 ac1 = (f32x4){0.f, 0.f, 0.f, 0.f};
        ac0 = __builtin_amdgcn_mfma_f32_16x16x32_bf16(a00, b0, ac0, 0, 0, 0);
        ac0 = __builtin_amdgcn_mfma_f32_16x16x32_bf16(a01, b1, ac0, 0, 0, 0);
        ac1 = __builtin_amdgcn_mfma_f32_16x16x32_bf16(a10, b0, ac1, 0, 0, 0);
        ac1 = __builtin_amdgcn_mfma_f32_16x16x32_bf16(a11, b1, ac1, 0, 0, 0);
        u4s p0, p1;
#pragma unroll
        for (int r = 0; r < 4; r++) {
            p0[r] = f2b(ac0[r] * 0.125f);
            p1[r] = f2b(ac1[r] * 0.125f);
        }
        *reinterpret_cast<u4s*>(&tpwT[co * 36 + lkg * 4]) = p0;
        *reinterpret_cast<u4s*>(&tpwT[co * 36 + 16 + lkg * 4]) = p1;
    }
    __syncthreads();

    s4v wsv[5][4];
#pragma unroll
    for (int q = 0; q < 5; q++)
#pragma unroll
        for (int j = 0; j < 4; j++)
            wsv[q][j] = *reinterpret_cast<const s4v*>(&tpwT[(q * 128 + c) * 36 + seg * 16 + j * 4]);

    float A[11], F[11];
#pragma unroll
    for (int q = 0; q < 11; q++) { A[q] = 0.f; F[q] = 0.f; }
    int cur_rc = rc_l[seg * 16];
    int Frc = -1;

#define STORE_RUN(RC, SRC) do { \
        float* ms = msg_s + (long)(RC) * 256 + c; \
        ms[0] = SRC[0]; ms[128] = SRC[1]; \
        float* mv = msg_v + (long)(RC) * 1152 + c; \
        mv[0] = SRC[2]; mv[128] = SRC[3]; mv[256] = SRC[4]; \
        mv[384] = SRC[5]; mv[512] = SRC[6]; mv[640] = SRC[7]; \
        mv[768] = SRC[8]; mv[896] = SRC[9]; mv[1024] = SRC[10]; \
    } while (0)
#define ATOM_RUN(RC, SRC) do { \
        float* ms = msg_s + (long)(RC) * 256 + c; \
        unsafeAtomicAdd(ms, SRC[0]); unsafeAtomicAdd(ms + 128, SRC[1]); \
        float* mv = msg_v + (long)(RC) * 1152 + c; \
        unsafeAtomicAdd(mv + 0, SRC[2]); unsafeAtomicAdd(mv + 128, SRC[3]); \
        unsafeAtomicAdd(mv + 256, SRC[4]); unsafeAtomicAdd(mv + 384, SRC[5]); \
        unsafeAtomicAdd(mv + 512, SRC[6]); unsafeAtomicAdd(mv + 640, SRC[7]); \
        unsafeAtomicAdd(mv + 768, SRC[8]); unsafeAtomicAdd(mv + 896, SRC[9]); \
        unsafeAtomicAdd(mv + 1024, SRC[10]); \
    } while (0)

#pragma unroll
    for (int i = 0; i < 16; i++) {
        int idx = seg * 16 + i;
        int rc = rc_l[idx];
        if (rc != cur_rc) {
            if (Frc < 0) {
#pragma unroll
                for (int q = 0; q < 11; q++) { F[q] = A[q]; A[q] = 0.f; }
                Frc = cur_rc;
            } else {
                STORE_RUN(cur_rc, A);
#pragma unroll
                for (int q = 0; q < 11; q++) A[q] = 0.f;
            }
            cur_rc = rc;
        }
        float es = es_l[idx], ev0 = ev_l[idx][0], ev1 = ev_l[idx][1], ev2 = ev_l[idx][2];
        float w1 = b2f((unsigned short)wsv[0][i >> 2][i & 3]);
        float w2 = b2f((unsigned short)wsv[1][i >> 2][i & 3]);
        float w3 = b2f((unsigned short)wsv[2][i >> 2][i & 3]);
        float w4 = b2f((unsigned short)wsv[3][i >> 2][i & 3]);
        float w5 = b2f((unsigned short)wsv[4][i >> 2][i & 3]);
        float xsv = b2f(xpr[i][0]);
        float x0 = b2f(xpr[i][1]), x1 = b2f(xpr[i][2]), x2 = b2f(xpr[i][3]);
        A[0] += w1 * xsv * es;
        float dve = x0 * ev0 + x1 * ev1 + x2 * ev2;
        A[1] += w4 * dve * 0.57735026919f;
        float a2 = w2 * xsv;
        A[2] += a2 * ev0;
        A[3] += w3 * x0 * es;
        A[4] += w5 * (x1 * ev2 - x2 * ev1) * 0.70710678119f;
        A[5] += a2 * ev1;
        A[6] += w3 * x1 * es;
        A[7] += w5 * (x2 * ev0 - x0 * ev2) * 0.70710678119f;
        A[8] += a2 * ev2;
        A[9] += w3 * x2 * es;
        A[10] += w5 * (x0 * ev1 - x1 * ev0) * 0.70710678119f;
    }
    const bool merge = (rc_l[15] == rc_l[16]);
    if (seg == 0) {
        if (merge) {
#pragma unroll
            for (int q = 0; q < 11; q++) mrg[c][q] = A[q];
            if (Frc >= 0) {
                if (bflags[0] == j0) STORE_RUN(Frc, F); else ATOM_RUN(Frc, F);
            }
        } else {
            if (Frc < 0) {
                if (bflags[0] == j0) STORE_RUN(cur_rc, A); else ATOM_RUN(cur_rc, A);
            } else {
                if (bflags[0] == j0) STORE_RUN(Frc, F); else ATOM_RUN(Frc, F);
                STORE_RUN(cur_rc, A);
            }
        }
    } else {
        if (!merge) {
            if (Frc < 0) {
                if (bflags[2] == j0 + 32) STORE_RUN(cur_rc, A); else ATOM_RUN(cur_rc, A);
            } else {
                STORE_RUN(Frc, F);
                if (bflags[2] == j0 + 32) STORE_RUN(cur_rc, A); else ATOM_RUN(cur_rc, A);
            }
        }
    }
    __syncthreads();
    if (seg == 1 && merge) {
        if (Frc < 0) {
#pragma unroll
            for (int q = 0; q < 11; q++) A[q] += mrg[c][q];
            bool st = (bflags[1] >= j0) && (bflags[2] == j0 + 32);
            if (st) STORE_RUN(cur_rc, A); else ATOM_RUN(cur_rc, A);
        } else {
#pragma unroll
            for (int q = 0; q < 11; q++) F[q] += mrg[c][q];
            if (bflags[1] >= j0) STORE_RUN(Frc, F); else ATOM_RUN(Frc, F);
            if (bflags[2] == j0 + 32) STORE_RUN(cur_rc, A); else ATOM_RUN(cur_rc, A);
        }
    }
#undef STORE_RUN
#undef ATOM_RUN
}

extern "C" void kernel_launch(void* const* d_in, const int* in_sizes, int n_in,
                              void* d_out, int out_size, void* d_ws, size_t ws_size,
                              hipStream_t stream) {
    const float* node_attrs = (const float*)d_in[0];
    const float* nfs        = (const float*)d_in[1];
    const float* nfv        = (const float*)d_in[2];
    const float* edge_attrs = (const float*)d_in[3];
    const float* edge_feats = (const float*)d_in[4];
    const float* W_sc_s     = (const float*)d_in[5];
    const float* W_sc_v     = (const float*)d_in[6];
    const float* W_lin_s    = (const float*)d_in[7];
    const float* W_lin_v    = (const float*)d_in[8];
    const float* mlp_w0     = (const float*)d_in[9];
    const float* mlp_w1     = (const float*)d_in[10];
    const float* mlp_w2     = (const float*)d_in[11];
    const float* mlp_w3     = (const float*)d_in[12];
    const float* W_out_s    = (const float*)d_in[13];
    const float* W_out_v    = (const float*)d_in[14];
    const int* senders      = (const int*)d_in[15];
    const int* receivers    = (const int*)d_in[16];
    float* dout = (float*)d_out;

    char* W = (char*)d_ws;
    unsigned short* xpack_ws = (unsigned short*)(W + 0);        // 10,240,000
    float* msgs_ws = (float*)(W + 10240000);   // 10,240,000
    float* msgv_ws = (float*)(W + 20480000);   // 46,080,000 -> ends 66,560,000
    // nfvT/nfsB alias the msgv region (consumed before memset/edge2 write it)
    unsigned short* nfvT_ws = (unsigned short*)(W + 20480000);  // 7,680,000
    unsigned short* nfsB_ws = (unsigned short*)(W + 28160000);  // 2,560,000 -> ends 30,720,000
    unsigned short* h2_ws   = (unsigned short*)(W + 66560000);  // 20,480,000 -> ends 87,040,000
    unsigned short* wsc_s2  = (unsigned short*)(W + 87040000);
    unsigned short* wsc_v2  = (unsigned short*)(W + 87367680);
    unsigned short* wlin_sT = (unsigned short*)(W + 87695360);
    unsigned short* wlin_vT = (unsigned short*)(W + 87728128);
    unsigned short* wout_sT = (unsigned short*)(W + 87760896);
    unsigned short* wout_vT = (unsigned short*)(W + 87826432);
    unsigned short* w3T     = (unsigned short*)(W + 87924736);
    unsigned short* w1T     = (unsigned short*)(W + 88006656);
    unsigned short* w2T     = (unsigned short*)(W + 88014848);
    int* cnt_ws   = (int*)(W + 88023040);
    int* base_ws  = (int*)(W + 88064000);
    int* cur_ws   = (int*)(W + 88104960);
    int* order_ws = (int*)(W + 88145920);   // ends 88,785,920

    const float inv1280 = 0.02795084972f;
    const float inv128  = 0.08838834765f;
    const float scO_s   = 1.f / 256.f;
    const float scO_v   = 1.f / (19.5959179423f * 16.f);

    k_prep<<<dim3(640, 11, 1), 256, 0, stream>>>(W_sc_s, W_sc_v, W_lin_s, W_lin_v, W_out_s, W_out_v, mlp_w3,
                                                 mlp_w1, mlp_w2, nfv, nfs,
                                                 wsc_s2, wsc_v2, wlin_sT, wlin_vT, wout_sT, wout_vT, w3T,
                                                 w1T, w2T, nfvT_ws, nfsB_ws);
    k_mlp012<<<dim3(2500), 256, 0, stream>>>(edge_feats, mlp_w0, w1T, w2T, h2_ws);

    // sc -> d_out second half  +  fused xpack (bf16 [n][c][4]), 64-row tile, 512 threads
    k_sc<<<dim3(157, 4), 512, 0, stream>>>(nfsB_ws, nfvT_ws, node_attrs, wsc_s2, wsc_v2,
                                           wlin_sT, wlin_vT, dout + 5120000, inv1280,
                                           xpack_ws, inv128);

    hipMemsetAsync(msgs_ws, 0, 56320000, stream);  // msg_s + msg_v (overwrites nfvT/nfsB alias)
    hipMemsetAsync(cnt_ws, 0, 40960, stream);
    k_hist<<<dim3(625), 256, 0, stream>>>(receivers, cnt_ws);
    k_scan<<<dim3(1), 256, 0, stream>>>(cnt_ws, base_ws, cur_ws);
    k_scatter<<<dim3(625), 256, 0, stream>>>(receivers, cur_ws, order_ws);
    k_edge2<<<dim3(5000), 256, 0, stream>>>(h2_ws, w3T, edge_attrs, senders, receivers, order_ws,
                                            base_ws, xpack_ws, msgs_ws, msgv_ws);

    // out = msg @ W_out -> d_out first half
    {
        GemmZ g0{msgs_ws,       256,  1, wout_sT, dout,           512, 1, 256, scO_s, N_NODES, 0, 0};
        GemmZ g1{msgv_ws + 0,   1152, 1, wout_vT, dout + 128 + 0, 512, 3, 384, scO_v, N_NODES, 0, 0};
        GemmZ g2{msgv_ws + 384, 1152, 1, wout_vT, dout + 128 + 1, 512, 3, 384, scO_v, N_NODES, 0, 0};
        GemmZ g3{msgv_ws + 768, 1152, 1, wout_vT, dout + 128 + 2, 512, 3, 384, scO_v, N_NODES, 0, 0};
        k_gemm<<<dim3(157, 1, 4), 256, 0, stream>>>(g0, g1, g2, g3);
    }
}

// Round 17
// 282.196 us; speedup vs baseline: 1.6109x; 1.0088x over previous
//
#include <hip/hip_runtime.h>

#define N_NODES 10000
#define N_EDGES 160000

typedef float f32x4 __attribute__((ext_vector_type(4)));
typedef short s8v __attribute__((ext_vector_type(8)));
typedef short s4v __attribute__((ext_vector_type(4)));
typedef unsigned short u4s __attribute__((ext_vector_type(4)));

__device__ __forceinline__ unsigned short f2b(float f) {
    unsigned u = __builtin_bit_cast(unsigned, f);
    u += 0x7FFFu + ((u >> 16) & 1u);
    return (unsigned short)(u >> 16);
}
__device__ __forceinline__ float b2f(unsigned short s) {
    unsigned u = ((unsigned)s) << 16;
    return __builtin_bit_cast(float, u);
}

// ---------------- prep: weights -> bf16 layouts; nfv transpose; nfs convert ----------------
__global__ void k_prep(const float* s0, const float* s1, const float* s2, const float* s3,
                       const float* s4, const float* s5, const float* s6,
                       const float* s7, const float* s8, const float* nfv, const float* nfs,
                       unsigned short* d0, unsigned short* d1, unsigned short* d2, unsigned short* d3,
                       unsigned short* d4, unsigned short* d5, unsigned short* d6,
                       unsigned short* d7, unsigned short* d8,
                       unsigned short* nfvT, unsigned short* nfsB) {
    int idx = blockIdx.x * 256 + threadIdx.x;
    if (blockIdx.y < 2) {
        const float* src = blockIdx.y ? s1 : s0;
        unsigned short* dst = blockIdx.y ? d1 : d0;
        int k = idx >> 7, o = idx & 127;
        int ci = k / 10, a = k - ci * 10;
        dst[a * 16384 + o * 128 + ci] = f2b(src[idx]);
        return;
    }
    if (blockIdx.y == 9) {
        // nfv [n][c][i] f32 -> nfvT [i][n][c] bf16
        for (int ch = idx; ch < 960000; ch += 163840) {
            f32x4 v = *reinterpret_cast<const f32x4*>(nfv + (long)ch * 4);
            int f0 = ch * 4;
            int n = f0 / 384, rem = f0 - n * 384;
#pragma unroll
            for (int j = 0; j < 4; j++) {
                int f = rem + j;
                int cc = f / 3, ii = f - cc * 3;
                nfvT[ii * 1280000 + n * 128 + cc] = f2b(v[j]);
            }
        }
        return;
    }
    if (blockIdx.y == 10) {
        for (int ch = idx; ch < 320000; ch += 163840) {
            f32x4 v = *reinterpret_cast<const f32x4*>(nfs + (long)ch * 4);
#pragma unroll
            for (int j = 0; j < 4; j++) nfsB[ch * 4 + j] = f2b(v[j]);
        }
        return;
    }
    const float* src; unsigned short* dst; int K, Nc;
    switch (blockIdx.y) {
        case 2: src = s2; dst = d2; K = 128;  Nc = 128; break;
        case 3: src = s3; dst = d3; K = 128;  Nc = 128; break;
        case 4: src = s4; dst = d4; K = 256;  Nc = 128; break;
        case 5: src = s5; dst = d5; K = 384;  Nc = 128; break;
        case 6: src = s6; dst = d6; K = 64;   Nc = 640; break;
        case 7: src = s7; dst = d7; K = 64;   Nc = 64;  break;
        default: src = s8; dst = d8; K = 64;  Nc = 64;  break;
    }
    if (idx < K * Nc) {
        int k = idx / Nc, c = idx - k * Nc;
        dst[c * K + k] = f2b(src[idx]);
    }
}

// ---------------- sc + xpack fused: 64x128 tile, 512 threads / 8 waves ----------------
// wave wv: rows (wv&3)*16..+16, cols (wv>>2)*64..+64
__global__ __launch_bounds__(512, 2) void k_sc(const unsigned short* __restrict__ nfsB,
                                               const unsigned short* __restrict__ nfvT,
                                               const float* __restrict__ attr,
                                               const unsigned short* __restrict__ Ws2,
                                               const unsigned short* __restrict__ Wv2,
                                               const unsigned short* __restrict__ wlin_sT,
                                               const unsigned short* __restrict__ wlin_vT,
                                               float* __restrict__ out, float scale,
                                               unsigned short* __restrict__ xpack, float scale2) {
    __shared__ unsigned short As[64][136];
    __shared__ unsigned short Bs[128][140];
    __shared__ float attr_l[64][10];
    const int t = threadIdx.x;
    const int z = blockIdx.y;
    const int row0 = blockIdx.x * 64;
    const int wv = t >> 6, lane = t & 63, lr = lane & 15, lkg = lane >> 4;
    const int wr = (wv & 3) * 16;       // wave row offset
    const int wc = (wv >> 2) * 64;      // wave col offset

    {
        int r = t >> 3, k0 = (t & 7) * 16;
        int row = row0 + r;
        if (row < N_NODES) {
            const unsigned short* asrc = (z == 0) ? (nfsB + (long)row * 128)
                                                  : (nfvT + (long)(z - 1) * 1280000 + (long)row * 128);
            *reinterpret_cast<s8v*>(&As[r][k0])     = *reinterpret_cast<const s8v*>(asrc + k0);
            *reinterpret_cast<s8v*>(&As[r][k0 + 8]) = *reinterpret_cast<const s8v*>(asrc + k0 + 8);
        } else {
#pragma unroll
            for (int j = 0; j < 16; j++) As[r][k0 + j] = 0;
        }
    }
    for (int idx = t; idx < 640; idx += 512) {
        int r = idx / 10, a = idx - r * 10;
        int row = row0 + r;
        attr_l[r][a] = (row < N_NODES) ? attr[row * 10 + a] : 0.f;
    }
    __syncthreads();

    s8v af[4];
#pragma unroll
    for (int kk = 0; kk < 4; kk++)
        af[kk] = *reinterpret_cast<const s8v*>(&As[wr + lr][kk * 32 + lkg * 8]);

    f32x4 accS[4];
#pragma unroll
    for (int i = 0; i < 4; i++) accS[i] = (f32x4){0.f, 0.f, 0.f, 0.f};

    const unsigned short* Wbase = (z == 0) ? Ws2 : Wv2;
    for (int a = 0; a < 10; a++) {
        {
            const unsigned short* src = Wbase + a * 16384;
            int r = t >> 2, c0 = (t & 3) * 32;
#pragma unroll
            for (int j = 0; j < 4; j++) {
                s8v v = *reinterpret_cast<const s8v*>(src + r * 128 + c0 + j * 8);
                *reinterpret_cast<s8v*>(&Bs[r][c0 + j * 8]) = v;
            }
        }
        __syncthreads();
        f32x4 acc[4];
#pragma unroll
        for (int i = 0; i < 4; i++) acc[i] = (f32x4){0.f, 0.f, 0.f, 0.f};
#pragma unroll
        for (int kk = 0; kk < 4; kk++) {
#pragma unroll
            for (int ct = 0; ct < 4; ct++) {
                s8v bf = *reinterpret_cast<const s8v*>(&Bs[wc + ct * 16 + lr][kk * 32 + lkg * 8]);
                acc[ct] = __builtin_amdgcn_mfma_f32_16x16x32_bf16(af[kk], bf, acc[ct], 0, 0, 0);
            }
        }
#pragma unroll
        for (int r = 0; r < 4; r++) {
            float aw = attr_l[wr + lkg * 4 + r][a];
#pragma unroll
            for (int ct = 0; ct < 4; ct++)
                accS[ct][r] += aw * acc[ct][r];
        }
        __syncthreads();
    }
#pragma unroll
    for (int ct = 0; ct < 4; ct++) {
#pragma unroll
        for (int r = 0; r < 4; r++) {
            int row = row0 + wr + lkg * 4 + r;
            if (row < N_NODES) {
                int col = wc + ct * 16 + lr;
                if (z == 0) out[(long)row * 512 + col] = accS[ct][r] * scale;
                else        out[(long)row * 512 + 128 + col * 3 + (z - 1)] = accS[ct][r] * scale;
            }
        }
    }
    // ---- fused xpack: x = A @ wlin * scale2 (reuses af fragments) ----
    {
        const unsigned short* wl = (z == 0) ? wlin_sT : wlin_vT;
        {
            int r = t >> 2, c0 = (t & 3) * 32;
#pragma unroll
            for (int j = 0; j < 4; j++) {
                s8v v = *reinterpret_cast<const s8v*>(wl + r * 128 + c0 + j * 8);
                *reinterpret_cast<s8v*>(&Bs[r][c0 + j * 8]) = v;
            }
        }
        __syncthreads();
        f32x4 acc[4];
#pragma unroll
        for (int i = 0; i < 4; i++) acc[i] = (f32x4){0.f, 0.f, 0.f, 0.f};
#pragma unroll
        for (int kk = 0; kk < 4; kk++) {
#pragma unroll
            for (int ct = 0; ct < 4; ct++) {
                s8v bf = *reinterpret_cast<const s8v*>(&Bs[wc + ct * 16 + lr][kk * 32 + lkg * 8]);
                acc[ct] = __builtin_amdgcn_mfma_f32_16x16x32_bf16(af[kk], bf, acc[ct], 0, 0, 0);
            }
        }
#pragma unroll
        for (int ct = 0; ct < 4; ct++) {
#pragma unroll
            for (int r = 0; r < 4; r++) {
                int row = row0 + wr + lkg * 4 + r;
                if (row < N_NODES) {
                    int col = wc + ct * 16 + lr;
                    xpack[(long)row * 512 + col * 4 + z] = f2b(acc[ct][r] * scale2);
                }
            }
        }
    }
}

// ---------------- generic MFMA GEMM (out GEMM): 64x128 tile, 512 threads / 8 waves ----------------
struct GemmZ {
    const float* Ap;
    int ars, aks;
    const unsigned short* Bt;
    float* Cp;
    int crs, ccs;
    int K;
    float scale;
    int M;
    int obf16;
    int abf16;
};

__global__ __launch_bounds__(512, 2) void k_gemm(GemmZ g0, GemmZ g1, GemmZ g2, GemmZ g3) {
    GemmZ g;
    switch (blockIdx.z) { case 0: g = g0; break; case 1: g = g1; break; case 2: g = g2; break; default: g = g3; }
    __shared__ unsigned short As[64][40];
    const int t = threadIdx.x;
    const int wv = t >> 6, lane = t & 63;
    const int lr = lane & 15, lkg = lane >> 4;
    const int row0 = blockIdx.x * 64;
    const int wr = (wv & 3) * 16;       // wave row offset
    const int wc = (wv >> 2) * 64;      // wave col offset
    const int br = t >> 3;              // staging row (0..63)
    const int bk0 = (t & 7) * 4;        // staging k offset (4 elems)
    const int arow = row0 + br;

    f32x4 acc[4];
#pragma unroll
    for (int i = 0; i < 4; i++) acc[i] = (f32x4){0.f, 0.f, 0.f, 0.f};

    for (int k0 = 0; k0 < g.K; k0 += 32) {
        s4v av;
        if (arow < g.M) {
            if (g.abf16) {
                const unsigned short* ap = (const unsigned short*)g.Ap + (long)arow * g.ars + k0 + bk0;
                av = *reinterpret_cast<const s4v*>(ap);
            } else if (g.aks == 1) {
                const float* ap = g.Ap + (long)arow * g.ars + k0 + bk0;
                f32x4 v0 = *reinterpret_cast<const f32x4*>(ap);
                av[0] = (short)f2b(v0[0]); av[1] = (short)f2b(v0[1]);
                av[2] = (short)f2b(v0[2]); av[3] = (short)f2b(v0[3]);
            } else {
#pragma unroll
                for (int j = 0; j < 4; j++)
                    av[j] = (short)f2b(g.Ap[(long)arow * g.ars + (long)(k0 + bk0 + j) * g.aks]);
            }
        } else {
#pragma unroll
            for (int j = 0; j < 4; j++) av[j] = 0;
        }
        __syncthreads();
        *reinterpret_cast<s4v*>(&As[br][bk0]) = av;
        __syncthreads();
        s8v af = *reinterpret_cast<const s8v*>(&As[wr + lr][lkg * 8]);
#pragma unroll
        for (int ct = 0; ct < 4; ct++) {
            const unsigned short* bp = g.Bt + (long)(wc + ct * 16 + lr) * g.K + k0 + lkg * 8;
            s8v bf = *reinterpret_cast<const s8v*>(bp);
            acc[ct] = __builtin_amdgcn_mfma_f32_16x16x32_bf16(af, bf, acc[ct], 0, 0, 0);
        }
    }
#pragma unroll
    for (int ct = 0; ct < 4; ct++) {
#pragma unroll
        for (int r = 0; r < 4; r++) {
            int row = row0 + wr + lkg * 4 + r;
            if (row < g.M) {
                int col = wc + ct * 16 + lr;
                if (g.obf16)
                    ((unsigned short*)g.Cp)[(long)row * g.crs + col * g.ccs] = f2b(acc[ct][r] * g.scale);
                else
                    g.Cp[(long)row * g.crs + col * g.ccs] = acc[ct][r] * g.scale;
            }
        }
    }
}

// ---------------- MLP: layer0 VALU, layers 1-2 MFMA ----------------
__global__ __launch_bounds__(256) void k_mlp012(const float* __restrict__ ef, const float* __restrict__ w0,
                                                const unsigned short* __restrict__ w1T,
                                                const unsigned short* __restrict__ w2T,
                                                unsigned short* __restrict__ h2out) {
    __shared__ float efs[64][8];
    __shared__ unsigned short hA[64][72];
    __shared__ unsigned short hB[64][72];
    const int t = threadIdx.x;
    const long e0 = (long)blockIdx.x * 64;
#pragma unroll
    for (int j = 0; j < 2; j++) { int idx = t + j * 256; ((float*)efs)[idx] = ef[e0 * 8 + idx]; }
    const int o = t & 63, ebase = t >> 6;
    float w0r[8];
#pragma unroll
    for (int k = 0; k < 8; k++) w0r[k] = w0[k * 64 + o];
    __syncthreads();
#pragma unroll
    for (int j = 0; j < 16; j++) {
        int e = ebase * 16 + j;
        float acc = 0.f;
#pragma unroll
        for (int k = 0; k < 8; k++) acc += efs[e][k] * w0r[k];
        acc *= 0.35355339059f;
        hA[e][o] = f2b(acc / (1.f + __expf(-acc)));
    }
    __syncthreads();
    const int wv = t >> 6, lane = t & 63, lr = lane & 15, lkg = lane >> 4;
    {
        f32x4 acc1[4];
#pragma unroll
        for (int ct = 0; ct < 4; ct++) acc1[ct] = (f32x4){0.f, 0.f, 0.f, 0.f};
#pragma unroll
        for (int kk = 0; kk < 2; kk++) {
            s8v a = *reinterpret_cast<const s8v*>(&hA[wv * 16 + lr][kk * 32 + lkg * 8]);
#pragma unroll
            for (int ct = 0; ct < 4; ct++) {
                s8v b = *reinterpret_cast<const s8v*>(w1T + (ct * 16 + lr) * 64 + kk * 32 + lkg * 8);
                acc1[ct] = __builtin_amdgcn_mfma_f32_16x16x32_bf16(a, b, acc1[ct], 0, 0, 0);
            }
        }
#pragma unroll
        for (int ct = 0; ct < 4; ct++)
#pragma unroll
            for (int r = 0; r < 4; r++) {
                float v = acc1[ct][r] * 0.125f;
                hB[wv * 16 + lkg * 4 + r][ct * 16 + lr] = f2b(v / (1.f + __expf(-v)));
            }
    }
    __syncthreads();
    {
        f32x4 acc2[4];
#pragma unroll
        for (int ct = 0; ct < 4; ct++) acc2[ct] = (f32x4){0.f, 0.f, 0.f, 0.f};
#pragma unroll
        for (int kk = 0; kk < 2; kk++) {
            s8v a = *reinterpret_cast<const s8v*>(&hB[wv * 16 + lr][kk * 32 + lkg * 8]);
#pragma unroll
            for (int ct = 0; ct < 4; ct++) {
                s8v b = *reinterpret_cast<const s8v*>(w2T + (ct * 16 + lr) * 64 + kk * 32 + lkg * 8);
                acc2[ct] = __builtin_amdgcn_mfma_f32_16x16x32_bf16(a, b, acc2[ct], 0, 0, 0);
            }
        }
#pragma unroll
        for (int ct = 0; ct < 4; ct++)
#pragma unroll
            for (int r = 0; r < 4; r++) {
                float v = acc2[ct][r] * 0.125f;
                int row = wv * 16 + lkg * 4 + r;
                h2out[(e0 + row) * 64 + ct * 16 + lr] = f2b(v / (1.f + __expf(-v)));
            }
    }
}

// ---------------- CSR build ----------------
__global__ void k_hist(const int* __restrict__ rcv, int* __restrict__ cnt) {
    int e = blockIdx.x * 256 + threadIdx.x;
    if (e < N_EDGES) atomicAdd(&cnt[rcv[e]], 1);
}

__global__ __launch_bounds__(256) void k_scan(const int* __restrict__ cnt, int* __restrict__ base, int* __restrict__ cur) {
    __shared__ int s[256];
    const int t = threadIdx.x;
    const int c0 = t * 40;
    int sum = 0;
    for (int i = 0; i < 40; i++) sum += cnt[c0 + i];
    s[t] = sum;
    __syncthreads();
    for (int off = 1; off < 256; off <<= 1) {
        int v = (t >= off) ? s[t - off] : 0;
        __syncthreads();
        s[t] += v;
        __syncthreads();
    }
    int run = t ? s[t - 1] : 0;
    for (int i = 0; i < 40; i++) {
        int idx = c0 + i;
        if (idx <= N_NODES) { base[idx] = run; cur[idx] = run; }
        run += cnt[idx];
    }
}

__global__ void k_scatter(const int* __restrict__ rcv, int* __restrict__ cur, int* __restrict__ order) {
    int e = blockIdx.x * 256 + threadIdx.x;
    if (e < N_EDGES) {
        int p = atomicAdd(&cur[rcv[e]], 1);
        order[p] = e;
    }
}

// ---------------- fused per-edge: early gathers, b-reuse MFMA, transposed tpw, store-runs ----------------
__global__ __launch_bounds__(256, 3) void k_edge2(const unsigned short* __restrict__ h2,
                                                  const unsigned short* __restrict__ w3T,
                                                  const float* __restrict__ eattr,
                                                  const int* __restrict__ snd, const int* __restrict__ rcv,
                                                  const int* __restrict__ order,
                                                  const int* __restrict__ base,
                                                  const unsigned short* __restrict__ xpack,
                                                  float* __restrict__ msg_s, float* __restrict__ msg_v) {
    __shared__ char smem_u[5760];                 // union: h2s [32][72] u16 | mrg [128][11] f32
    __shared__ unsigned short tpwT[640 * 36];     // [col][edge], stride 36 u16 (72B, 8B-aligned)
    __shared__ float es_l[32];
    __shared__ float ev_l[32][3];
    __shared__ int sn_l[32], rc_l[32];
    __shared__ int bflags[3];
    unsigned short (*h2s)[72] = (unsigned short(*)[72])smem_u;
    float (*mrg)[11] = (float(*)[11])smem_u;
    const int t = threadIdx.x;
    const int j0 = blockIdx.x * 32;
    {
        int r = t >> 3, kk = (t & 7) * 8;
        int e = order[j0 + r];
        s8v v = *reinterpret_cast<const s8v*>(h2 + (long)e * 64 + kk);
        *reinterpret_cast<s8v*>(&h2s[r][kk]) = v;
    }
    if (t < 32) {
        int e = order[j0 + t];
        es_l[t] = eattr[e * 4 + 0];
        ev_l[t][0] = eattr[e * 4 + 1];
        ev_l[t][1] = eattr[e * 4 + 2];
        ev_l[t][2] = eattr[e * 4 + 3];
        sn_l[t] = snd[e];
        int rc = rcv[e];
        rc_l[t] = rc;
        if (t == 0)  bflags[0] = base[rc];
        if (t == 16) bflags[1] = base[rc];
        if (t == 31) bflags[2] = base[rc + 1];
    }
    __syncthreads();
    const int wv = t >> 6, lane = t & 63, lr = lane & 15, lkg = lane >> 4;
    const int c = t & 127, seg = t >> 7;

    // T14 async-split: issue the 16 random xpack gathers NOW; latency hides under MFMA phase
    u4s xpr[16];
#pragma unroll
    for (int i = 0; i < 16; i++)
        xpr[i] = *reinterpret_cast<const u4s*>(xpack + (long)sn_l[seg * 16 + i] * 512 + c * 4);

    s8v a00 = *reinterpret_cast<const s8v*>(&h2s[lr][lkg * 8]);
    s8v a01 = *reinterpret_cast<const s8v*>(&h2s[lr][32 + lkg * 8]);
    s8v a10 = *reinterpret_cast<const s8v*>(&h2s[16 + lr][lkg * 8]);
    s8v a11 = *reinterpret_cast<const s8v*>(&h2s[16 + lr][32 + lkg * 8]);
#pragma unroll
    for (int q = 0; q < 10; q++) {
        int co = (wv + 4 * q) * 16 + lr;
        const unsigned short* bp = w3T + (long)co * 64 + lkg * 8;
        s8v b0 = *reinterpret_cast<const s8v*>(bp);
        s8v b1 = *reinterpret_cast<const s8v*>(bp + 32);
        f32x4 ac0 = (f32x4){0.f, 0.f, 0.f, 0.f};
        f32x4 ac1 = (f32x4){0.f, 0.f, 0.f, 0.f};
        ac0 = __builtin_amdgcn_mfma_f32_16x16x32_bf16(a00, b0, ac0, 0, 0, 0);
        ac0 = __builtin_amdgcn_mfma_f32_16x16x32_bf16(a01, b1, ac0, 0, 0, 0);
        ac1 = __builtin_amdgcn_mfma_f32_16x16x32_bf16(a10, b0, ac1, 0, 0, 0);
        ac1 = __builtin_amdgcn_mfma_f32_16x16x32_bf16(a11, b1, ac1, 0, 0, 0);
        u4s p0, p1;
#pragma unroll
        for (int r = 0; r < 4; r++) {
            p0[r] = f2b(ac0[r] * 0.125f);
            p1[r] = f2b(ac1[r] * 0.125f);
        }
        *reinterpret_cast<u4s*>(&tpwT[co * 36 + lkg * 4]) = p0;
        *reinterpret_cast<u4s*>(&tpwT[co * 36 + 16 + lkg * 4]) = p1;
    }
    __syncthreads();

    s4v wsv[5][4];
#pragma unroll
    for (int q = 0; q < 5; q++)
#pragma unroll
        for (int j = 0; j < 4; j++)
            wsv[q][j] = *reinterpret_cast<const s4v*>(&tpwT[(q * 128 + c) * 36 + seg * 16 + j * 4]);

    float A[11], F[11];
#pragma unroll
    for (int q = 0; q < 11; q++) { A[q] = 0.f; F[q] = 0.f; }
    int cur_rc = rc_l[seg * 16];
    int Frc = -1;

#define STORE_RUN(RC, SRC) do { \
        float* ms = msg_s + (long)(RC) * 256 + c; \
        ms[0] = SRC[0]; ms[128] = SRC[1]; \
        float* mv = msg_v + (long)(RC) * 1152 + c; \
        mv[0] = SRC[2]; mv[128] = SRC[3]; mv[256] = SRC[4]; \
        mv[384] = SRC[5]; mv[512] = SRC[6]; mv[640] = SRC[7]; \
        mv[768] = SRC[8]; mv[896] = SRC[9]; mv[1024] = SRC[10]; \
    } while (0)
#define ATOM_RUN(RC, SRC) do { \
        float* ms = msg_s + (long)(RC) * 256 + c; \
        unsafeAtomicAdd(ms, SRC[0]); unsafeAtomicAdd(ms + 128, SRC[1]); \
        float* mv = msg_v + (long)(RC) * 1152 + c; \
        unsafeAtomicAdd(mv + 0, SRC[2]); unsafeAtomicAdd(mv + 128, SRC[3]); \
        unsafeAtomicAdd(mv + 256, SRC[4]); unsafeAtomicAdd(mv + 384, SRC[5]); \
        unsafeAtomicAdd(mv + 512, SRC[6]); unsafeAtomicAdd(mv + 640, SRC[7]); \
        unsafeAtomicAdd(mv + 768, SRC[8]); unsafeAtomicAdd(mv + 896, SRC[9]); \
        unsafeAtomicAdd(mv + 1024, SRC[10]); \
    } while (0)

#pragma unroll
    for (int i = 0; i < 16; i++) {
        int idx = seg * 16 + i;
        int rc = rc_l[idx];
        if (rc != cur_rc) {
            if (Frc < 0) {
#pragma unroll
                for (int q = 0; q < 11; q++) { F[q] = A[q]; A[q] = 0.f; }
                Frc = cur_rc;
            } else {
                STORE_RUN(cur_rc, A);
#pragma unroll
                for (int q = 0; q < 11; q++) A[q] = 0.f;
            }
            cur_rc = rc;
        }
        float es = es_l[idx], ev0 = ev_l[idx][0], ev1 = ev_l[idx][1], ev2 = ev_l[idx][2];
        float w1 = b2f((unsigned short)wsv[0][i >> 2][i & 3]);
        float w2 = b2f((unsigned short)wsv[1][i >> 2][i & 3]);
        float w3 = b2f((unsigned short)wsv[2][i >> 2][i & 3]);
        float w4 = b2f((unsigned short)wsv[3][i >> 2][i & 3]);
        float w5 = b2f((unsigned short)wsv[4][i >> 2][i & 3]);
        float xsv = b2f(xpr[i][0]);
        float x0 = b2f(xpr[i][1]), x1 = b2f(xpr[i][2]), x2 = b2f(xpr[i][3]);
        A[0] += w1 * xsv * es;
        float dve = x0 * ev0 + x1 * ev1 + x2 * ev2;
        A[1] += w4 * dve * 0.57735026919f;
        float a2 = w2 * xsv;
        A[2] += a2 * ev0;
        A[3] += w3 * x0 * es;
        A[4] += w5 * (x1 * ev2 - x2 * ev1) * 0.70710678119f;
        A[5] += a2 * ev1;
        A[6] += w3 * x1 * es;
        A[7] += w5 * (x2 * ev0 - x0 * ev2) * 0.70710678119f;
        A[8] += a2 * ev2;
        A[9] += w3 * x2 * es;
        A[10] += w5 * (x0 * ev1 - x1 * ev0) * 0.70710678119f;
    }
    const bool merge = (rc_l[15] == rc_l[16]);
    if (seg == 0) {
        if (merge) {
#pragma unroll
            for (int q = 0; q < 11; q++) mrg[c][q] = A[q];
            if (Frc >= 0) {
                if (bflags[0] == j0) STORE_RUN(Frc, F); else ATOM_RUN(Frc, F);
            }
        } else {
            if (Frc < 0) {
                if (bflags[0] == j0) STORE_RUN(cur_rc, A); else ATOM_RUN(cur_rc, A);
            } else {
                if (bflags[0] == j0) STORE_RUN(Frc, F); else ATOM_RUN(Frc, F);
                STORE_RUN(cur_rc, A);
            }
        }
    } else {
        if (!merge) {
            if (Frc < 0) {
                if (bflags[2] == j0 + 32) STORE_RUN(cur_rc, A); else ATOM_RUN(cur_rc, A);
            } else {
                STORE_RUN(Frc, F);
                if (bflags[2] == j0 + 32) STORE_RUN(cur_rc, A); else ATOM_RUN(cur_rc, A);
            }
        }
    }
    __syncthreads();
    if (seg == 1 && merge) {
        if (Frc < 0) {
#pragma unroll
            for (int q = 0; q < 11; q++) A[q] += mrg[c][q];
            bool st = (bflags[1] >= j0) && (bflags[2] == j0 + 32);
            if (st) STORE_RUN(cur_rc, A); else ATOM_RUN(cur_rc, A);
        } else {
#pragma unroll
            for (int q = 0; q < 11; q++) F[q] += mrg[c][q];
            if (bflags[1] >= j0) STORE_RUN(Frc, F); else ATOM_RUN(Frc, F);
            if (bflags[2] == j0 + 32) STORE_RUN(cur_rc, A); else ATOM_RUN(cur_rc, A);
        }
    }
#undef STORE_RUN
#undef ATOM_RUN
}

extern "C" void kernel_launch(void* const* d_in, const int* in_sizes, int n_in,
                              void* d_out, int out_size, void* d_ws, size_t ws_size,
                              hipStream_t stream) {
    const float* node_attrs = (const float*)d_in[0];
    const float* nfs        = (const float*)d_in[1];
    const float* nfv        = (const float*)d_in[2];
    const float* edge_attrs = (const float*)d_in[3];
    const float* edge_feats = (const float*)d_in[4];
    const float* W_sc_s     = (const float*)d_in[5];
    const float* W_sc_v     = (const float*)d_in[6];
    const float* W_lin_s    = (const float*)d_in[7];
    const float* W_lin_v    = (const float*)d_in[8];
    const float* mlp_w0     = (const float*)d_in[9];
    const float* mlp_w1     = (const float*)d_in[10];
    const float* mlp_w2     = (const float*)d_in[11];
    const float* mlp_w3     = (const float*)d_in[12];
    const float* W_out_s    = (const float*)d_in[13];
    const float* W_out_v    = (const float*)d_in[14];
    const int* senders      = (const int*)d_in[15];
    const int* receivers    = (const int*)d_in[16];
    float* dout = (float*)d_out;

    char* W = (char*)d_ws;
    unsigned short* xpack_ws = (unsigned short*)(W + 0);        // 10,240,000
    float* msgs_ws = (float*)(W + 10240000);   // 10,240,000
    float* msgv_ws = (float*)(W + 20480000);   // 46,080,000 -> ends 66,560,000
    // nfvT/nfsB alias the msgv region (consumed before memset/edge2 write it)
    unsigned short* nfvT_ws = (unsigned short*)(W + 20480000);  // 7,680,000
    unsigned short* nfsB_ws = (unsigned short*)(W + 28160000);  // 2,560,000 -> ends 30,720,000
    unsigned short* h2_ws   = (unsigned short*)(W + 66560000);  // 20,480,000 -> ends 87,040,000
    unsigned short* wsc_s2  = (unsigned short*)(W + 87040000);
    unsigned short* wsc_v2  = (unsigned short*)(W + 87367680);
    unsigned short* wlin_sT = (unsigned short*)(W + 87695360);
    unsigned short* wlin_vT = (unsigned short*)(W + 87728128);
    unsigned short* wout_sT = (unsigned short*)(W + 87760896);
    unsigned short* wout_vT = (unsigned short*)(W + 87826432);
    unsigned short* w3T     = (unsigned short*)(W + 87924736);
    unsigned short* w1T     = (unsigned short*)(W + 88006656);
    unsigned short* w2T     = (unsigned short*)(W + 88014848);
    int* cnt_ws   = (int*)(W + 88023040);
    int* base_ws  = (int*)(W + 88064000);
    int* cur_ws   = (int*)(W + 88104960);
    int* order_ws = (int*)(W + 88145920);   // ends 88,785,920

    const float inv1280 = 0.02795084972f;
    const float inv128  = 0.08838834765f;
    const float scO_s   = 1.f / 256.f;
    const float scO_v   = 1.f / (19.5959179423f * 16.f);

    k_prep<<<dim3(640, 11, 1), 256, 0, stream>>>(W_sc_s, W_sc_v, W_lin_s, W_lin_v, W_out_s, W_out_v, mlp_w3,
                                                 mlp_w1, mlp_w2, nfv, nfs,
                                                 wsc_s2, wsc_v2, wlin_sT, wlin_vT, wout_sT, wout_vT, w3T,
                                                 w1T, w2T, nfvT_ws, nfsB_ws);
    k_mlp012<<<dim3(2500), 256, 0, stream>>>(edge_feats, mlp_w0, w1T, w2T, h2_ws);

    // sc -> d_out second half  +  fused xpack (bf16 [n][c][4]), 64-row tile, 512 threads
    k_sc<<<dim3(157, 4), 512, 0, stream>>>(nfsB_ws, nfvT_ws, node_attrs, wsc_s2, wsc_v2,
                                           wlin_sT, wlin_vT, dout + 5120000, inv1280,
                                           xpack_ws, inv128);

    hipMemsetAsync(msgs_ws, 0, 56320000, stream);  // msg_s + msg_v (overwrites nfvT/nfsB alias)
    hipMemsetAsync(cnt_ws, 0, 40960, stream);
    k_hist<<<dim3(625), 256, 0, stream>>>(receivers, cnt_ws);
    k_scan<<<dim3(1), 256, 0, stream>>>(cnt_ws, base_ws, cur_ws);
    k_scatter<<<dim3(625), 256, 0, stream>>>(receivers, cur_ws, order_ws);
    k_edge2<<<dim3(5000), 256, 0, stream>>>(h2_ws, w3T, edge_attrs, senders, receivers, order_ws,
                                            base_ws, xpack_ws, msgs_ws, msgv_ws);

    // out = msg @ W_out -> d_out first half (512-thread blocks)
    {
        GemmZ g0{msgs_ws,       256,  1, wout_sT, dout,           512, 1, 256, scO_s, N_NODES, 0, 0};
        GemmZ g1{msgv_ws + 0,   1152, 1, wout_vT, dout + 128 + 0, 512, 3, 384, scO_v, N_NODES, 0, 0};
        GemmZ g2{msgv_ws + 384, 1152, 1, wout_vT, dout + 128 + 1, 512, 3, 384, scO_v, N_NODES, 0, 0};
        GemmZ g3{msgv_ws + 768, 1152, 1, wout_vT, dout + 128 + 2, 512, 3, 384, scO_v, N_NODES, 0, 0};
        k_gemm<<<dim3(157, 1, 4), 512, 0, stream>>>(g0, g1, g2, g3);
    }
}